// Round 1
// baseline (1379.776 us; speedup 1.0000x reference)
//
#include <hip/hip_runtime.h>
#include <hip/hip_bf16.h>
#include <stdint.h>

// ---------------- problem constants ----------------
#define D_MODEL 2048
#define D_STATE 16
#define DT_RANK 128
#define B_SZ 4
#define SEQLEN 2048
#define MROWS (B_SZ * SEQLEN)          // 8192
#define NPROJ (DT_RANK + 2 * D_STATE)  // 160

typedef short bf16x8 __attribute__((ext_vector_type(8)));           // 8 bf16 (4 VGPRs) MFMA A/B frag
typedef unsigned short ushort8 __attribute__((ext_vector_type(8)));
typedef float f32x4 __attribute__((ext_vector_type(4)));            // MFMA C/D frag

// f32 -> bf16 round-to-nearest-even (no NaN handling; inputs are finite)
__device__ __forceinline__ unsigned short f2bf(float f) {
  union { float f; uint32_t u; } a; a.f = f;
  uint32_t u = a.u;
  u += 0x7fffu + ((u >> 16) & 1u);
  return (unsigned short)(u >> 16);
}
__device__ __forceinline__ float bf2f(unsigned short h) {
  union { uint32_t u; float f; } a; a.u = ((uint32_t)h) << 16;
  return a.f;
}

// async global->LDS, 16B per lane. LDS dest must be wave-uniform base; HW adds lane*16.
__device__ __forceinline__ void async16(const void* g, void* l) {
  __builtin_amdgcn_global_load_lds((const __attribute__((address_space(1))) void*)g,
                                   (__attribute__((address_space(3))) void*)(uintptr_t)l,
                                   16, 0, 0);
}

// ---------------------------------------------------------------------------
// Generic NT GEMM: C[M,N] = A[M,K] (row-major) * B[N,K]^T (row-major N x K).
// BK = 32 fixed. 256 threads = 4 waves arranged WMv x WNv.
// A_BF/B_BF: operand already bf16 in global (use global_load_lds) vs f32
// (register-stage + convert + ds_write).
// EPI: 0 = x-proj (store f32 [*,160] + bf16 dtmp for col<128)
//      1 = delta  (softplus(acc + dt_bias), store bf16 [*,2048])
//      2 = out    (relu(acc + out_bias) + D*hs, store f32 [*,2048])
// ---------------------------------------------------------------------------
template<int BM, int BN, int WMv, int WNv, bool A_BF, bool B_BF, int EPI>
__global__ __launch_bounds__(256)
void gemm_nt(const float* __restrict__ Af, const unsigned short* __restrict__ Ab,
             const float* __restrict__ Bf, const unsigned short* __restrict__ Bb,
             int K,
             float* __restrict__ outf, unsigned short* __restrict__ outb,
             const float* __restrict__ bias, const float* __restrict__ Dvec,
             const float* __restrict__ hsres)
{
  constexpr int TM = BM / WMv, TN = BN / WNv;
  constexpr int FM = TM / 16, FN = TN / 16;
  __shared__ char smem[(BM + BN) * 64];   // [BM][32] bf16 A-tile, then [BN][32] bf16 B-tile
  char* smA = smem;
  char* smB = smem + BM * 64;

  const int tid  = threadIdx.x;
  const int lane = tid & 63;
  const int wid  = tid >> 6;
  const int wm   = wid / WNv, wn = wid % WNv;
  const int wrow = wm * TM,  wcol = wn * TN;
  const int row0 = blockIdx.x * BM;
  const int col0 = blockIdx.y * BN;

  f32x4 acc[FM][FN] = {};

  for (int k0 = 0; k0 < K; k0 += 32) {
    // ---- stage A tile [BM][32] ----
    if constexpr (A_BF) {
      #pragma unroll
      for (int it = 0; it < (BM * 4) / 256; ++it) {
        int c = it * 256 + tid;
        const char* g = (const char*)(Ab + (size_t)(row0 + (c >> 2)) * K + k0) + (c & 3) * 16;
        async16(g, smA + it * 4096 + (tid & ~63) * 16);
      }
    } else {
      constexpr int CH = BM * 4;
      #pragma unroll
      for (int it = 0; it < (CH + 255) / 256; ++it) {
        int c = it * 256 + tid;
        if ((CH % 256 == 0) || (c < CH)) {
          const float* g = Af + (size_t)(row0 + (c >> 2)) * K + k0 + (c & 3) * 8;
          float4 u = *reinterpret_cast<const float4*>(g);
          float4 v = *reinterpret_cast<const float4*>(g + 4);
          ushort8 p;
          p[0] = f2bf(u.x); p[1] = f2bf(u.y); p[2] = f2bf(u.z); p[3] = f2bf(u.w);
          p[4] = f2bf(v.x); p[5] = f2bf(v.y); p[6] = f2bf(v.z); p[7] = f2bf(v.w);
          *reinterpret_cast<ushort8*>(smA + c * 16) = p;
        }
      }
    }
    // ---- stage B tile [BN][32] ----
    if constexpr (B_BF) {
      #pragma unroll
      for (int it = 0; it < (BN * 4) / 256; ++it) {
        int c = it * 256 + tid;
        const char* g = (const char*)(Bb + (size_t)(col0 + (c >> 2)) * K + k0) + (c & 3) * 16;
        async16(g, smB + it * 4096 + (tid & ~63) * 16);
      }
    } else {
      constexpr int CH = BN * 4;
      #pragma unroll
      for (int it = 0; it < (CH + 255) / 256; ++it) {
        int c = it * 256 + tid;
        if ((CH % 256 == 0) || (c < CH)) {
          const float* g = Bf + (size_t)(col0 + (c >> 2)) * K + k0 + (c & 3) * 8;
          float4 u = *reinterpret_cast<const float4*>(g);
          float4 v = *reinterpret_cast<const float4*>(g + 4);
          ushort8 p;
          p[0] = f2bf(u.x); p[1] = f2bf(u.y); p[2] = f2bf(u.z); p[3] = f2bf(u.w);
          p[4] = f2bf(v.x); p[5] = f2bf(v.y); p[6] = f2bf(v.z); p[7] = f2bf(v.w);
          *reinterpret_cast<ushort8*>(smB + c * 16) = p;
        }
      }
    }
    __syncthreads();   // drains vmcnt (global_load_lds) + lgkm (ds_write)

    // ---- fragments + MFMA ----
    // A-frag: lane l holds A[row = l&15][k = 8*(l>>4) + i], i=0..7  -> ds_read_b128
    bf16x8 a[FM], b[FN];
    const int kb = (lane >> 4) * 16;   // byte offset of this lane's 8 bf16 within a 64B row
    #pragma unroll
    for (int i = 0; i < FM; ++i)
      a[i] = *reinterpret_cast<const bf16x8*>(smA + (wrow + i * 16 + (lane & 15)) * 64 + kb);
    #pragma unroll
    for (int j = 0; j < FN; ++j)
      b[j] = *reinterpret_cast<const bf16x8*>(smB + (wcol + j * 16 + (lane & 15)) * 64 + kb);
    #pragma unroll
    for (int i = 0; i < FM; ++i)
      #pragma unroll
      for (int j = 0; j < FN; ++j)
        acc[i][j] = __builtin_amdgcn_mfma_f32_16x16x32_bf16(a[i], b[j], acc[i][j], 0, 0, 0);
    __syncthreads();
  }

  // ---- epilogue: D mapping row=(lane>>4)*4+reg, col=lane&15 (verified m89) ----
  #pragma unroll
  for (int i = 0; i < FM; ++i) {
    #pragma unroll
    for (int j = 0; j < FN; ++j) {
      #pragma unroll
      for (int r = 0; r < 4; ++r) {
        int grow = row0 + wrow + i * 16 + ((lane >> 4) * 4) + r;
        int gcol = col0 + wcol + j * 16 + (lane & 15);
        float v = acc[i][j][r];
        if constexpr (EPI == 0) {
          outf[(size_t)grow * NPROJ + gcol] = v;
          if (gcol < DT_RANK) outb[(size_t)grow * DT_RANK + gcol] = f2bf(v);
        } else if constexpr (EPI == 1) {
          float s = v + bias[gcol];
          s = (s > 20.f) ? s : log1pf(__expf(s));
          outb[(size_t)grow * D_MODEL + gcol] = f2bf(s);
        } else {
          float s = fmaxf(v + bias[gcol], 0.f)
                    + Dvec[gcol] * hsres[(size_t)grow * D_MODEL + gcol];
          outf[(size_t)grow * D_MODEL + gcol] = s;
        }
      }
    }
  }
}

// ---------------------------------------------------------------------------
// Sequential selective scan. Block = 256 threads = 16 d-lanes x 16 states,
// one batch b per blockIdx.y, 16 d per blockIdx.x. h lives in a register.
// y_t[d] = sum_n h[d][n] * C[t][n]  via 16-lane shfl_xor reduce.
// ---------------------------------------------------------------------------
__global__ __launch_bounds__(256)
void scan_kernel(const unsigned short* __restrict__ delta,
                 const float* __restrict__ hs,
                 const float* __restrict__ xdbc,
                 const float* __restrict__ A_log,
                 unsigned short* __restrict__ y)
{
  const int b  = blockIdx.y;
  const int d0 = blockIdx.x * 16;
  const int n  = threadIdx.x & 15;
  const int dl = threadIdx.x >> 4;
  const int d  = d0 + dl;
  const float A_dn = -__expf(A_log[d * D_STATE + n]);
  float h = 0.f;
  const unsigned short* dp = delta + (size_t)b * SEQLEN * D_MODEL + d;
  const float* xp = hs   + (size_t)b * SEQLEN * D_MODEL + d;
  const float* bp = xdbc + (size_t)b * SEQLEN * NPROJ + DT_RANK + n;
  const float* cp = bp + D_STATE;
  unsigned short* yp = y + (size_t)b * SEQLEN * D_MODEL + d;
  #pragma unroll 4
  for (int t = 0; t < SEQLEN; ++t) {
    float dlt = bf2f(dp[(size_t)t * D_MODEL]);
    float x   = xp[(size_t)t * D_MODEL];
    float Bt  = bp[(size_t)t * NPROJ];
    float Ct  = cp[(size_t)t * NPROJ];
    float dA  = __expf(dlt * A_dn);
    h = fmaf(h, dA, dlt * x * Bt);
    float v = h * Ct;
    v += __shfl_xor(v, 1);
    v += __shfl_xor(v, 2);
    v += __shfl_xor(v, 4);
    v += __shfl_xor(v, 8);
    if (n == 0) yp[(size_t)t * D_MODEL] = f2bf(v);
  }
}

// f32 -> bf16 cast, 8 elements/thread (for out_proj_weight)
__global__ __launch_bounds__(256)
void cast_kernel(const float* __restrict__ in, unsigned short* __restrict__ out)
{
  int i = (blockIdx.x * 256 + threadIdx.x) * 8;
  float4 u = *reinterpret_cast<const float4*>(in + i);
  float4 v = *reinterpret_cast<const float4*>(in + i + 4);
  ushort8 p;
  p[0] = f2bf(u.x); p[1] = f2bf(u.y); p[2] = f2bf(u.z); p[3] = f2bf(u.w);
  p[4] = f2bf(v.x); p[5] = f2bf(v.y); p[6] = f2bf(v.z); p[7] = f2bf(v.w);
  *reinterpret_cast<ushort8*>(out + i) = p;
}

// ---------------------------------------------------------------------------
extern "C" void kernel_launch(void* const* d_in, const int* in_sizes, int n_in,
                              void* d_out, int out_size, void* d_ws, size_t ws_size,
                              hipStream_t stream)
{
  const float* hs   = (const float*)d_in[0];  // (4,2048,2048)
  const float* xpw  = (const float*)d_in[1];  // (160,2048)
  const float* dtw  = (const float*)d_in[2];  // (2048,128)
  const float* dtb  = (const float*)d_in[3];  // (2048,)
  const float* Alog = (const float*)d_in[4];  // (2048,16)
  const float* Dv   = (const float*)d_in[5];  // (2048,)
  const float* opw  = (const float*)d_in[6];  // (2048,2048)
  const float* opb  = (const float*)d_in[7];  // (2048,)
  float* out = (float*)d_out;

  char* ws = (char*)d_ws;
  float*          xdbc  = (float*)(ws);                         // 8192*160 f32   = 5,242,880 B
  unsigned short* dtmp  = (unsigned short*)(ws + 5242880);      // 8192*128 bf16  = 2,097,152 B
  unsigned short* delta = (unsigned short*)(ws + 7340032);      // 8192*2048 bf16 = 33,554,432 B
  unsigned short* ybf   = (unsigned short*)(ws + 40894464);     // 8192*2048 bf16 = 33,554,432 B
  unsigned short* w3b   = (unsigned short*)(ws + 74448896);     // 2048*2048 bf16 = 8,388,608 B
  // total ws use: 82,837,504 B

  // out_proj_weight -> bf16
  cast_kernel<<<dim3((D_MODEL * D_MODEL) / (256 * 8)), 256, 0, stream>>>(opw, w3b);

  // GEMM1: xdbc[8192,160] = hs @ x_proj_weight^T ; also dtmp = bf16(xdbc[:, :128])
  gemm_nt<64, 32, 2, 2, false, false, 0>
      <<<dim3(MROWS / 64, NPROJ / 32), 256, 0, stream>>>(
      hs, nullptr, xpw, nullptr, D_MODEL, xdbc, dtmp, nullptr, nullptr, nullptr);

  // GEMM2: delta[8192,2048] = softplus(dtmp @ dt_proj_weight^T + dt_bias) (bf16)
  gemm_nt<128, 128, 2, 2, true, false, 1>
      <<<dim3(MROWS / 128, D_MODEL / 128), 256, 0, stream>>>(
      nullptr, dtmp, dtw, nullptr, DT_RANK, nullptr, delta, dtb, nullptr, nullptr);

  // Scan: y_bf16[8192,2048]
  scan_kernel<<<dim3(D_MODEL / 16, B_SZ), 256, 0, stream>>>(delta, hs, xdbc, Alog, ybf);

  // GEMM3: out = relu(y @ out_proj^T + out_bias) + D*hs
  gemm_nt<128, 128, 2, 2, true, true, 2>
      <<<dim3(MROWS / 128, D_MODEL / 128), 256, 0, stream>>>(
      nullptr, ybf, nullptr, w3b, D_MODEL, out, nullptr, opb, Dv, hs);

  (void)in_sizes; (void)n_in; (void)out_size; (void)ws_size;
}

// Round 2
// 491.557 us; speedup vs baseline: 2.8070x; 2.8070x over previous
//
#include <hip/hip_runtime.h>
#include <hip/hip_bf16.h>
#include <stdint.h>

// ---------------- problem constants ----------------
#define D_MODEL 2048
#define D_STATE 16
#define DT_RANK 128
#define B_SZ 4
#define SEQLEN 2048
#define MROWS (B_SZ * SEQLEN)          // 8192
#define NPROJ (DT_RANK + 2 * D_STATE)  // 160
#define NCHUNK 32
#define CHUNK (SEQLEN / NCHUNK)        // 64

typedef short bf16x8 __attribute__((ext_vector_type(8)));           // 8 bf16 (4 VGPRs) MFMA A/B frag
typedef unsigned short ushort8 __attribute__((ext_vector_type(8)));
typedef float f32x4 __attribute__((ext_vector_type(4)));            // MFMA C/D frag

// f32 -> bf16 round-to-nearest-even (no NaN handling; inputs are finite)
__device__ __forceinline__ unsigned short f2bf(float f) {
  union { float f; uint32_t u; } a; a.f = f;
  uint32_t u = a.u;
  u += 0x7fffu + ((u >> 16) & 1u);
  return (unsigned short)(u >> 16);
}
__device__ __forceinline__ float bf2f(unsigned short h) {
  union { uint32_t u; float f; } a; a.u = ((uint32_t)h) << 16;
  return a.f;
}

// async global->LDS, 16B per lane. LDS dest must be wave-uniform base; HW adds lane*16.
__device__ __forceinline__ void async16(const void* g, void* l) {
  __builtin_amdgcn_global_load_lds((const __attribute__((address_space(1))) void*)g,
                                   (__attribute__((address_space(3))) void*)(uintptr_t)l,
                                   16, 0, 0);
}

// ---------------------------------------------------------------------------
// Generic NT GEMM: C[M,N] = A[M,K] (row-major) * B[N,K]^T (row-major N x K).
// BK = 32 fixed. 256 threads = 4 waves arranged WMv x WNv.
// ---------------------------------------------------------------------------
template<int BM, int BN, int WMv, int WNv, bool A_BF, bool B_BF, int EPI>
__global__ __launch_bounds__(256)
void gemm_nt(const float* __restrict__ Af, const unsigned short* __restrict__ Ab,
             const float* __restrict__ Bf, const unsigned short* __restrict__ Bb,
             int K,
             float* __restrict__ outf, unsigned short* __restrict__ outb,
             const float* __restrict__ bias, const float* __restrict__ Dvec,
             const float* __restrict__ hsres)
{
  constexpr int TM = BM / WMv, TN = BN / WNv;
  constexpr int FM = TM / 16, FN = TN / 16;
  __shared__ char smem[(BM + BN) * 64];   // [BM][32] bf16 A-tile, then [BN][32] bf16 B-tile
  char* smA = smem;
  char* smB = smem + BM * 64;

  const int tid  = threadIdx.x;
  const int lane = tid & 63;
  const int wid  = tid >> 6;
  const int wm   = wid / WNv, wn = wid % WNv;
  const int wrow = wm * TM,  wcol = wn * TN;
  const int row0 = blockIdx.x * BM;
  const int col0 = blockIdx.y * BN;

  f32x4 acc[FM][FN] = {};

  for (int k0 = 0; k0 < K; k0 += 32) {
    // ---- stage A tile [BM][32] ----
    if constexpr (A_BF) {
      #pragma unroll
      for (int it = 0; it < (BM * 4) / 256; ++it) {
        int c = it * 256 + tid;
        const char* g = (const char*)(Ab + (size_t)(row0 + (c >> 2)) * K + k0) + (c & 3) * 16;
        async16(g, smA + it * 4096 + (tid & ~63) * 16);
      }
    } else {
      constexpr int CH = BM * 4;
      #pragma unroll
      for (int it = 0; it < (CH + 255) / 256; ++it) {
        int c = it * 256 + tid;
        if ((CH % 256 == 0) || (c < CH)) {
          const float* g = Af + (size_t)(row0 + (c >> 2)) * K + k0 + (c & 3) * 8;
          float4 u = *reinterpret_cast<const float4*>(g);
          float4 v = *reinterpret_cast<const float4*>(g + 4);
          ushort8 p;
          p[0] = f2bf(u.x); p[1] = f2bf(u.y); p[2] = f2bf(u.z); p[3] = f2bf(u.w);
          p[4] = f2bf(v.x); p[5] = f2bf(v.y); p[6] = f2bf(v.z); p[7] = f2bf(v.w);
          *reinterpret_cast<ushort8*>(smA + c * 16) = p;
        }
      }
    }
    // ---- stage B tile [BN][32] ----
    if constexpr (B_BF) {
      #pragma unroll
      for (int it = 0; it < (BN * 4) / 256; ++it) {
        int c = it * 256 + tid;
        const char* g = (const char*)(Bb + (size_t)(col0 + (c >> 2)) * K + k0) + (c & 3) * 16;
        async16(g, smB + it * 4096 + (tid & ~63) * 16);
      }
    } else {
      constexpr int CH = BN * 4;
      #pragma unroll
      for (int it = 0; it < (CH + 255) / 256; ++it) {
        int c = it * 256 + tid;
        if ((CH % 256 == 0) || (c < CH)) {
          const float* g = Bf + (size_t)(col0 + (c >> 2)) * K + k0 + (c & 3) * 8;
          float4 u = *reinterpret_cast<const float4*>(g);
          float4 v = *reinterpret_cast<const float4*>(g + 4);
          ushort8 p;
          p[0] = f2bf(u.x); p[1] = f2bf(u.y); p[2] = f2bf(u.z); p[3] = f2bf(u.w);
          p[4] = f2bf(v.x); p[5] = f2bf(v.y); p[6] = f2bf(v.z); p[7] = f2bf(v.w);
          *reinterpret_cast<ushort8*>(smB + c * 16) = p;
        }
      }
    }
    __syncthreads();   // drains vmcnt (global_load_lds) + lgkm (ds_write)

    // ---- fragments + MFMA ----
    bf16x8 a[FM], b[FN];
    const int kb = (lane >> 4) * 16;   // byte offset of this lane's 8 bf16 within a 64B row
    #pragma unroll
    for (int i = 0; i < FM; ++i)
      a[i] = *reinterpret_cast<const bf16x8*>(smA + (wrow + i * 16 + (lane & 15)) * 64 + kb);
    #pragma unroll
    for (int j = 0; j < FN; ++j)
      b[j] = *reinterpret_cast<const bf16x8*>(smB + (wcol + j * 16 + (lane & 15)) * 64 + kb);
    #pragma unroll
    for (int i = 0; i < FM; ++i)
      #pragma unroll
      for (int j = 0; j < FN; ++j)
        acc[i][j] = __builtin_amdgcn_mfma_f32_16x16x32_bf16(a[i], b[j], acc[i][j], 0, 0, 0);
    __syncthreads();
  }

  // ---- epilogue: D mapping row=(lane>>4)*4+reg, col=lane&15 (verified m89) ----
  #pragma unroll
  for (int i = 0; i < FM; ++i) {
    #pragma unroll
    for (int j = 0; j < FN; ++j) {
      #pragma unroll
      for (int r = 0; r < 4; ++r) {
        int grow = row0 + wrow + i * 16 + ((lane >> 4) * 4) + r;
        int gcol = col0 + wcol + j * 16 + (lane & 15);
        float v = acc[i][j][r];
        if constexpr (EPI == 0) {
          outf[(size_t)grow * NPROJ + gcol] = v;
          if (gcol < DT_RANK) outb[(size_t)grow * DT_RANK + gcol] = f2bf(v);
        } else if constexpr (EPI == 1) {
          float s = v + bias[gcol];
          s = (s > 20.f) ? s : log1pf(__expf(s));
          outb[(size_t)grow * D_MODEL + gcol] = f2bf(s);
        } else {
          float s = fmaxf(v + bias[gcol], 0.f)
                    + Dvec[gcol] * hsres[(size_t)grow * D_MODEL + gcol];
          outf[(size_t)grow * D_MODEL + gcol] = s;
        }
      }
    }
  }
}

// ---------------------------------------------------------------------------
// Chunked selective scan. Thread owns one d and all 16 states in registers.
// P1 (P2=false): compute chunk-local h from 0; store Ssum (=sum of delta over
//                chunk) and Hloc. Decay product is exp(A_n * Ssum) - exact.
// P2 (P2=true):  init h from Hinit, recompute recurrence, emit y (bf16).
// ---------------------------------------------------------------------------
template<bool P2>
__global__ __launch_bounds__(256)
void scan_chunk(const unsigned short* __restrict__ delta,
                const float* __restrict__ hs,
                const float* __restrict__ xdbc,
                const float* __restrict__ A_log,
                float* __restrict__ Ssum, float* __restrict__ Hloc,
                const float* __restrict__ Hinit,
                unsigned short* __restrict__ y)
{
  const int b  = blockIdx.z;
  const int c  = blockIdx.y;
  const int d  = blockIdx.x * 256 + threadIdx.x;
  const int t0 = c * CHUNK;
  __shared__ float Bs[CHUNK][16];
  __shared__ float Cs[P2 ? CHUNK : 1][16];

  // stage B (and C) rows for this chunk: uniform-per-t broadcast values
  {
    int tt = threadIdx.x >> 2, nn = (threadIdx.x & 3) * 4;
    const float* src = xdbc + (size_t)(b * SEQLEN + t0 + tt) * NPROJ + DT_RANK;
    *reinterpret_cast<float4*>(&Bs[tt][nn]) = *reinterpret_cast<const float4*>(src + nn);
    if constexpr (P2)
      *reinterpret_cast<float4*>(&Cs[tt][nn]) = *reinterpret_cast<const float4*>(src + D_STATE + nn);
  }

  float A[16], h[16];
  #pragma unroll
  for (int n = 0; n < 16; ++n) A[n] = -__expf(A_log[d * 16 + n]);
  const size_t hoff = ((size_t)((b * NCHUNK + c) * D_MODEL) + d) * 16;
  if constexpr (P2) {
    #pragma unroll
    for (int n = 0; n < 16; ++n) h[n] = Hinit[hoff + n];
  } else {
    #pragma unroll
    for (int n = 0; n < 16; ++n) h[n] = 0.f;
  }
  __syncthreads();

  float S = 0.f;
  const size_t rbase = (size_t)(b * SEQLEN + t0) * D_MODEL + d;
  #pragma unroll 2
  for (int t = 0; t < CHUNK; ++t) {
    float dlt = bf2f(delta[rbase + (size_t)t * D_MODEL]);
    float x   = hs[rbase + (size_t)t * D_MODEL];
    float dx  = dlt * x;
    S += dlt;
    float yv = 0.f;
    #pragma unroll
    for (int n = 0; n < 16; ++n) {
      float dA = __expf(dlt * A[n]);
      h[n] = fmaf(h[n], dA, dx * Bs[t][n]);
      if constexpr (P2) yv = fmaf(h[n], Cs[t][n], yv);
    }
    if constexpr (P2) y[rbase + (size_t)t * D_MODEL] = f2bf(yv);
  }

  if constexpr (!P2) {
    Ssum[(size_t)((b * NCHUNK + c) * D_MODEL) + d] = S;
    #pragma unroll
    for (int n = 0; n < 16; ++n) Hloc[hoff + n] = h[n];
  }
}

// Inter-chunk propagation: per (b,d,n) lane, sequential over 32 chunks.
__global__ __launch_bounds__(256)
void scan_prop(const float* __restrict__ A_log, const float* __restrict__ Ssum,
               const float* __restrict__ Hloc, float* __restrict__ Hinit)
{
  int idx = blockIdx.x * 256 + threadIdx.x;            // [b][d][n]
  int n = idx & 15, d = (idx >> 4) & (D_MODEL - 1), b = idx >> 15;
  float A = -__expf(A_log[d * D_STATE + n]);
  float H = 0.f;
  for (int c = 0; c < NCHUNK; ++c) {
    size_t off = ((size_t)((b * NCHUNK + c) * D_MODEL) + d) * 16 + n;
    Hinit[off] = H;
    float P = __expf(A * Ssum[(size_t)((b * NCHUNK + c) * D_MODEL) + d]);
    H = fmaf(H, P, Hloc[off]);
  }
}

// f32 -> bf16 cast, 8 elements/thread (for out_proj_weight)
__global__ __launch_bounds__(256)
void cast_kernel(const float* __restrict__ in, unsigned short* __restrict__ out)
{
  int i = (blockIdx.x * 256 + threadIdx.x) * 8;
  float4 u = *reinterpret_cast<const float4*>(in + i);
  float4 v = *reinterpret_cast<const float4*>(in + i + 4);
  ushort8 p;
  p[0] = f2bf(u.x); p[1] = f2bf(u.y); p[2] = f2bf(u.z); p[3] = f2bf(u.w);
  p[4] = f2bf(v.x); p[5] = f2bf(v.y); p[6] = f2bf(v.z); p[7] = f2bf(v.w);
  *reinterpret_cast<ushort8*>(out + i) = p;
}

// ---------------------------------------------------------------------------
extern "C" void kernel_launch(void* const* d_in, const int* in_sizes, int n_in,
                              void* d_out, int out_size, void* d_ws, size_t ws_size,
                              hipStream_t stream)
{
  const float* hs   = (const float*)d_in[0];  // (4,2048,2048)
  const float* xpw  = (const float*)d_in[1];  // (160,2048)
  const float* dtw  = (const float*)d_in[2];  // (2048,128)
  const float* dtb  = (const float*)d_in[3];  // (2048,)
  const float* Alog = (const float*)d_in[4];  // (2048,16)
  const float* Dv   = (const float*)d_in[5];  // (2048,)
  const float* opw  = (const float*)d_in[6];  // (2048,2048)
  const float* opb  = (const float*)d_in[7];  // (2048,)
  float* out = (float*)d_out;

  char* ws = (char*)d_ws;
  float*          xdbc  = (float*)(ws);                         // 8192*160 f32   = 5,242,880 B
  unsigned short* dtmp  = (unsigned short*)(ws + 5242880);      // 8192*128 bf16  = 2,097,152 B
  unsigned short* delta = (unsigned short*)(ws + 7340032);      // 8192*2048 bf16 = 33,554,432 B
  unsigned short* ybf   = (unsigned short*)(ws + 40894464);     // 8192*2048 bf16 = 33,554,432 B
  unsigned short* w3b   = (unsigned short*)(ws + 74448896);     // 2048*2048 bf16 = 8,388,608 B
  float*          Hloc  = (float*)(ws + 82837504);              // 4*32*2048*16 f32 = 16,777,216 B
  float*          Hinit = (float*)(ws + 99614720);              // 16,777,216 B
  float*          Ssum  = (float*)(ws + 116391936);             // 4*32*2048 f32 = 1,048,576 B
  // total ws use: 117,440,512 B

  // out_proj_weight -> bf16
  cast_kernel<<<dim3((D_MODEL * D_MODEL) / (256 * 8)), 256, 0, stream>>>(opw, w3b);

  // GEMM1: xdbc[8192,160] = hs @ x_proj_weight^T ; also dtmp = bf16(xdbc[:, :128])
  gemm_nt<64, 32, 2, 2, false, false, 0>
      <<<dim3(MROWS / 64, NPROJ / 32), 256, 0, stream>>>(
      hs, nullptr, xpw, nullptr, D_MODEL, xdbc, dtmp, nullptr, nullptr, nullptr);

  // GEMM2: delta[8192,2048] = softplus(dtmp @ dt_proj_weight^T + dt_bias) (bf16)
  gemm_nt<128, 128, 2, 2, true, false, 1>
      <<<dim3(MROWS / 128, D_MODEL / 128), 256, 0, stream>>>(
      nullptr, dtmp, dtw, nullptr, DT_RANK, nullptr, delta, dtb, nullptr, nullptr);

  // Chunked scan: P1 -> prop -> P2
  scan_chunk<false><<<dim3(D_MODEL / 256, NCHUNK, B_SZ), 256, 0, stream>>>(
      delta, hs, xdbc, Alog, Ssum, Hloc, nullptr, nullptr);
  scan_prop<<<dim3((B_SZ * D_MODEL * D_STATE) / 256), 256, 0, stream>>>(
      Alog, Ssum, Hloc, Hinit);
  scan_chunk<true><<<dim3(D_MODEL / 256, NCHUNK, B_SZ), 256, 0, stream>>>(
      delta, hs, xdbc, Alog, nullptr, nullptr, Hinit, ybf);

  // GEMM3: out = relu(y @ out_proj^T + out_bias) + D*hs
  gemm_nt<128, 128, 2, 2, true, true, 2>
      <<<dim3(MROWS / 128, D_MODEL / 128), 256, 0, stream>>>(
      nullptr, ybf, nullptr, w3b, D_MODEL, out, nullptr, opb, Dv, hs);

  (void)in_sizes; (void)n_in; (void)out_size; (void)ws_size;
}

// Round 4
// 474.254 us; speedup vs baseline: 2.9094x; 1.0365x over previous
//
#include <hip/hip_runtime.h>
#include <hip/hip_bf16.h>
#include <stdint.h>

// ---------------- problem constants ----------------
#define D_MODEL 2048
#define D_STATE 16
#define DT_RANK 128
#define B_SZ 4
#define SEQLEN 2048
#define MROWS (B_SZ * SEQLEN)          // 8192
#define NPROJ (DT_RANK + 2 * D_STATE)  // 160
#define NCHUNK 32
#define CHUNK (SEQLEN / NCHUNK)        // 64

typedef short bf16x8 __attribute__((ext_vector_type(8)));
typedef unsigned short ushort8 __attribute__((ext_vector_type(8)));
typedef float f32x4 __attribute__((ext_vector_type(4)));

__device__ __forceinline__ unsigned short f2bf(float f) {
  union { float f; uint32_t u; } a; a.f = f;
  uint32_t u = a.u;
  u += 0x7fffu + ((u >> 16) & 1u);
  return (unsigned short)(u >> 16);
}
__device__ __forceinline__ float bf2f(unsigned short h) {
  union { uint32_t u; float f; } a; a.u = ((uint32_t)h) << 16;
  return a.f;
}

__device__ __forceinline__ void async16(const void* g, void* l) {
  __builtin_amdgcn_global_load_lds((const __attribute__((address_space(1))) void*)g,
                                   (__attribute__((address_space(3))) void*)(uintptr_t)l,
                                   16, 0, 0);
}

// ---------------------------------------------------------------------------
// gemm_big: C[M,2048] = A[M,K]*B[2048,K]^T, all bf16 operands.
// Tile 256x128, BK=64, 512 threads = 8 waves (4M x 2N), wave tile 64x64.
// 3-buffer LDS ring (144KB), prefetch depth 2 K-tiles, ONE barrier + ONE
// counted vmcnt(6) per K-tile (T3/T4). XOR swizzle byte^=(row&7)<<4 applied
// via pre-swizzled global source chunks + swizzled ds_read (T2, rule #21).
// setprio around MFMA cluster (T5). XCD-swizzled 1D grid (T1), n-major.
// EPI: 1 = softplus->bf16 (delta), 2 = relu(+bias)+D*hs -> f32 (out).
// ---------------------------------------------------------------------------
template<int EPI>
__global__ __launch_bounds__(512, 2)
void gemm_big(const unsigned short* __restrict__ A, const unsigned short* __restrict__ B,
              int K,
              float* __restrict__ outf, unsigned short* __restrict__ outb,
              const float* __restrict__ bias, const float* __restrict__ Dvec,
              const float* __restrict__ hsres)
{
  __shared__ char lds[3 * 49152];        // buf q: A 32KB ([256][128B]) + B 16KB ([128][128B])

  const int tid  = threadIdx.x;
  const int lane = tid & 63;
  const int wid  = tid >> 6;
  const int wrow = (wid >> 1) * 64;      // 4 M-waves
  const int wcol = (wid & 1) * 64;       // 2 N-waves
  // XCD-aware bijective swizzle (nwg = 512, 512 % 8 == 0)
  const int nwg = gridDim.x;
  const int cpx = nwg >> 3;
  const int swz = (blockIdx.x & 7) * cpx + (blockIdx.x >> 3);
  const int mb  = swz >> 4;              // N/128 = 16 col-blocks, n-major within m-panel
  const int nb  = swz & 15;
  const int row0 = mb * 256;
  const int col0 = nb * 128;

  const int nt = K >> 6;

  // stage one K-tile into buffer q: per-thread 4 A-chunks + 2 B-chunks (16B each).
  // LDS dest linear in chunk c; global source chunk = c ^ ((c>>3)&7)  (pre-swizzle).
  auto stage_tile = [&](int t, int q) {
    const int k0 = t * 64;
    char* bufA = lds + q * 49152;
    char* bufB = bufA + 32768;
    #pragma unroll
    for (int it = 0; it < 4; ++it) {
      int c = it * 512 + tid;
      int gc = c ^ ((c >> 3) & 7);
      const char* g = (const char*)(A + (size_t)(row0 + (gc >> 3)) * K + k0) + (gc & 7) * 16;
      async16(g, bufA + (c & ~63) * 16);
    }
    #pragma unroll
    for (int it = 0; it < 2; ++it) {
      int c = it * 512 + tid;
      int gc = c ^ ((c >> 3) & 7);
      const char* g = (const char*)(B + (size_t)(col0 + (gc >> 3)) * K + k0) + (gc & 7) * 16;
      async16(g, bufB + (c & ~63) * 16);
    }
  };

  f32x4 acc[4][4] = {};

  stage_tile(0, 0);
  stage_tile(1, 1);

  for (int t = 0; t < nt; ++t) {
    // tile t's 6 loads are the oldest; tile t+1's 6 may stay in flight.
    if (t < nt - 1) asm volatile("s_waitcnt vmcnt(6)" ::: "memory");
    else            asm volatile("s_waitcnt vmcnt(0)" ::: "memory");
    __builtin_amdgcn_s_barrier();        // all waves' tile-t loads visible; prev reads done
    if (t + 2 < nt) stage_tile(t + 2, (t + 2) % 3);

    const char* bufA = lds + (t % 3) * 49152;
    const char* bufB = bufA + 32768;
    #pragma unroll
    for (int kk = 0; kk < 2; ++kk) {
      bf16x8 a[4], b[4];
      #pragma unroll
      for (int i = 0; i < 4; ++i) {
        int r = wrow + i * 16 + (lane & 15);
        int byt = r * 128 + kk * 64 + ((lane >> 4) * 16);
        a[i] = *reinterpret_cast<const bf16x8*>(bufA + (byt ^ ((r & 7) << 4)));
      }
      #pragma unroll
      for (int j = 0; j < 4; ++j) {
        int r = wcol + j * 16 + (lane & 15);
        int byt = r * 128 + kk * 64 + ((lane >> 4) * 16);
        b[j] = *reinterpret_cast<const bf16x8*>(bufB + (byt ^ ((r & 7) << 4)));
      }
      __builtin_amdgcn_s_setprio(1);
      #pragma unroll
      for (int i = 0; i < 4; ++i)
        #pragma unroll
        for (int j = 0; j < 4; ++j)
          acc[i][j] = __builtin_amdgcn_mfma_f32_16x16x32_bf16(a[i], b[j], acc[i][j], 0, 0, 0);
      __builtin_amdgcn_s_setprio(0);
    }
  }

  // epilogue: D frag row=(lane>>4)*4+r, col=lane&15
  #pragma unroll
  for (int i = 0; i < 4; ++i) {
    #pragma unroll
    for (int j = 0; j < 4; ++j) {
      #pragma unroll
      for (int r = 0; r < 4; ++r) {
        int grow = row0 + wrow + i * 16 + ((lane >> 4) * 4) + r;
        int gcol = col0 + wcol + j * 16 + (lane & 15);
        float v = acc[i][j][r];
        if constexpr (EPI == 1) {
          float s = v + bias[gcol];
          s = (s > 20.f) ? s : log1pf(__expf(s));
          outb[(size_t)grow * D_MODEL + gcol] = f2bf(s);
        } else {
          float s = fmaxf(v + bias[gcol], 0.f)
                    + Dvec[gcol] * hsres[(size_t)grow * D_MODEL + gcol];
          outf[(size_t)grow * D_MODEL + gcol] = s;
        }
      }
    }
  }
}

// ---------------------------------------------------------------------------
// Small NT GEMM (GEMM1): C[M,160] = A[M,2048](f32) * B[160,2048](bf16)^T.
// BK=32, 256 threads, 4 waves 2x2. Single column pass (BN = 160).
// ---------------------------------------------------------------------------
template<int BM, int BN, int WMv, int WNv, bool A_BF, bool B_BF, int EPI>
__global__ __launch_bounds__(256)
void gemm_nt(const float* __restrict__ Af, const unsigned short* __restrict__ Ab,
             const float* __restrict__ Bf, const unsigned short* __restrict__ Bb,
             int K,
             float* __restrict__ outf, unsigned short* __restrict__ outb,
             const float* __restrict__ bias)
{
  constexpr int TM = BM / WMv, TN = BN / WNv;
  constexpr int FM = TM / 16, FN = TN / 16;
  __shared__ char smem[(BM + BN) * 64];
  char* smA = smem;
  char* smB = smem + BM * 64;

  const int tid  = threadIdx.x;
  const int lane = tid & 63;
  const int wid  = tid >> 6;
  const int wm   = wid / WNv, wn = wid % WNv;
  const int wrow = wm * TM,  wcol = wn * TN;
  const int row0 = blockIdx.x * BM;
  const int col0 = blockIdx.y * BN;

  f32x4 acc[FM][FN] = {};

  for (int k0 = 0; k0 < K; k0 += 32) {
    { // A tile
      constexpr int CH = BM * 4;
      #pragma unroll
      for (int it = 0; it < (CH + 255) / 256; ++it) {
        int c = it * 256 + tid;
        if ((CH % 256 == 0) || (c < CH)) {
          if constexpr (A_BF) {
            const char* g = (const char*)(Ab + (size_t)(row0 + (c >> 2)) * K + k0) + (c & 3) * 16;
            async16(g, smA + (c & ~63) * 16);
          } else {
            const float* g = Af + (size_t)(row0 + (c >> 2)) * K + k0 + (c & 3) * 8;
            float4 u = *reinterpret_cast<const float4*>(g);
            float4 v = *reinterpret_cast<const float4*>(g + 4);
            ushort8 p;
            p[0] = f2bf(u.x); p[1] = f2bf(u.y); p[2] = f2bf(u.z); p[3] = f2bf(u.w);
            p[4] = f2bf(v.x); p[5] = f2bf(v.y); p[6] = f2bf(v.z); p[7] = f2bf(v.w);
            *reinterpret_cast<ushort8*>(smA + c * 16) = p;
          }
        }
      }
    }
    { // B tile
      constexpr int CH = BN * 4;
      #pragma unroll
      for (int it = 0; it < (CH + 255) / 256; ++it) {
        int c = it * 256 + tid;
        if ((CH % 256 == 0) || (c < CH)) {
          if constexpr (B_BF) {
            const char* g = (const char*)(Bb + (size_t)(col0 + (c >> 2)) * K + k0) + (c & 3) * 16;
            async16(g, smB + (c & ~63) * 16);
          } else {
            const float* g = Bf + (size_t)(col0 + (c >> 2)) * K + k0 + (c & 3) * 8;
            float4 u = *reinterpret_cast<const float4*>(g);
            float4 v = *reinterpret_cast<const float4*>(g + 4);
            ushort8 p;
            p[0] = f2bf(u.x); p[1] = f2bf(u.y); p[2] = f2bf(u.z); p[3] = f2bf(u.w);
            p[4] = f2bf(v.x); p[5] = f2bf(v.y); p[6] = f2bf(v.z); p[7] = f2bf(v.w);
            *reinterpret_cast<ushort8*>(smB + c * 16) = p;
          }
        }
      }
    }
    __syncthreads();

    bf16x8 a[FM], b[FN];
    const int kb = (lane >> 4) * 16;
    #pragma unroll
    for (int i = 0; i < FM; ++i)
      a[i] = *reinterpret_cast<const bf16x8*>(smA + (wrow + i * 16 + (lane & 15)) * 64 + kb);
    #pragma unroll
    for (int j = 0; j < FN; ++j)
      b[j] = *reinterpret_cast<const bf16x8*>(smB + (wcol + j * 16 + (lane & 15)) * 64 + kb);
    #pragma unroll
    for (int i = 0; i < FM; ++i)
      #pragma unroll
      for (int j = 0; j < FN; ++j)
        acc[i][j] = __builtin_amdgcn_mfma_f32_16x16x32_bf16(a[i], b[j], acc[i][j], 0, 0, 0);
    __syncthreads();
  }

  #pragma unroll
  for (int i = 0; i < FM; ++i) {
    #pragma unroll
    for (int j = 0; j < FN; ++j) {
      #pragma unroll
      for (int r = 0; r < 4; ++r) {
        int grow = row0 + wrow + i * 16 + ((lane >> 4) * 4) + r;
        int gcol = col0 + wcol + j * 16 + (lane & 15);
        float v = acc[i][j][r];
        if constexpr (EPI == 0) {
          outf[(size_t)grow * NPROJ + gcol] = v;
          if (gcol < DT_RANK) outb[(size_t)grow * DT_RANK + gcol] = f2bf(v);
        } else {
          float s = v + bias[gcol];
          s = (s > 20.f) ? s : log1pf(__expf(s));
          outb[(size_t)grow * D_MODEL + gcol] = f2bf(s);
        }
      }
    }
  }
}

// ---------------------------------------------------------------------------
// Chunked selective scan (unchanged from R1).
// ---------------------------------------------------------------------------
template<bool P2>
__global__ __launch_bounds__(256)
void scan_chunk(const unsigned short* __restrict__ delta,
                const float* __restrict__ hs,
                const float* __restrict__ xdbc,
                const float* __restrict__ A_log,
                float* __restrict__ Ssum, float* __restrict__ Hloc,
                const float* __restrict__ Hinit,
                unsigned short* __restrict__ y)
{
  const int b  = blockIdx.z;
  const int c  = blockIdx.y;
  const int d  = blockIdx.x * 256 + threadIdx.x;
  const int t0 = c * CHUNK;
  __shared__ float Bs[CHUNK][16];
  __shared__ float Cs[P2 ? CHUNK : 1][16];

  {
    int tt = threadIdx.x >> 2, nn = (threadIdx.x & 3) * 4;
    const float* src = xdbc + (size_t)(b * SEQLEN + t0 + tt) * NPROJ + DT_RANK;
    *reinterpret_cast<float4*>(&Bs[tt][nn]) = *reinterpret_cast<const float4*>(src + nn);
    if constexpr (P2)
      *reinterpret_cast<float4*>(&Cs[tt][nn]) = *reinterpret_cast<const float4*>(src + D_STATE + nn);
  }

  float A[16], h[16];
  #pragma unroll
  for (int n = 0; n < 16; ++n) A[n] = -__expf(A_log[d * 16 + n]);
  const size_t hoff = ((size_t)((b * NCHUNK + c) * D_MODEL) + d) * 16;
  if constexpr (P2) {
    #pragma unroll
    for (int n = 0; n < 16; ++n) h[n] = Hinit[hoff + n];
  } else {
    #pragma unroll
    for (int n = 0; n < 16; ++n) h[n] = 0.f;
  }
  __syncthreads();

  float S = 0.f;
  const size_t rbase = (size_t)(b * SEQLEN + t0) * D_MODEL + d;
  #pragma unroll 2
  for (int t = 0; t < CHUNK; ++t) {
    float dlt = bf2f(delta[rbase + (size_t)t * D_MODEL]);
    float x   = hs[rbase + (size_t)t * D_MODEL];
    float dx  = dlt * x;
    S += dlt;
    float yv = 0.f;
    #pragma unroll
    for (int n = 0; n < 16; ++n) {
      float dA = __expf(dlt * A[n]);
      h[n] = fmaf(h[n], dA, dx * Bs[t][n]);
      if constexpr (P2) yv = fmaf(h[n], Cs[t][n], yv);
    }
    if constexpr (P2) y[rbase + (size_t)t * D_MODEL] = f2bf(yv);
  }

  if constexpr (!P2) {
    Ssum[(size_t)((b * NCHUNK + c) * D_MODEL) + d] = S;
    #pragma unroll
    for (int n = 0; n < 16; ++n) Hloc[hoff + n] = h[n];
  }
}

__global__ __launch_bounds__(256)
void scan_prop(const float* __restrict__ A_log, const float* __restrict__ Ssum,
               const float* __restrict__ Hloc, float* __restrict__ Hinit)
{
  int idx = blockIdx.x * 256 + threadIdx.x;
  int n = idx & 15, d = (idx >> 4) & (D_MODEL - 1), b = idx >> 15;
  float A = -__expf(A_log[d * D_STATE + n]);
  float H = 0.f;
  for (int c = 0; c < NCHUNK; ++c) {
    size_t off = ((size_t)((b * NCHUNK + c) * D_MODEL) + d) * 16 + n;
    Hinit[off] = H;
    float P = __expf(A * Ssum[(size_t)((b * NCHUNK + c) * D_MODEL) + d]);
    H = fmaf(H, P, Hloc[off]);
  }
}

__global__ __launch_bounds__(256)
void cast_kernel(const float* __restrict__ in, unsigned short* __restrict__ out)
{
  int i = (blockIdx.x * 256 + threadIdx.x) * 8;
  float4 u = *reinterpret_cast<const float4*>(in + i);
  float4 v = *reinterpret_cast<const float4*>(in + i + 4);
  ushort8 p;
  p[0] = f2bf(u.x); p[1] = f2bf(u.y); p[2] = f2bf(u.z); p[3] = f2bf(u.w);
  p[4] = f2bf(v.x); p[5] = f2bf(v.y); p[6] = f2bf(v.z); p[7] = f2bf(v.w);
  *reinterpret_cast<ushort8*>(out + i) = p;
}

// ---------------------------------------------------------------------------
extern "C" void kernel_launch(void* const* d_in, const int* in_sizes, int n_in,
                              void* d_out, int out_size, void* d_ws, size_t ws_size,
                              hipStream_t stream)
{
  const float* hs   = (const float*)d_in[0];
  const float* xpw  = (const float*)d_in[1];
  const float* dtw  = (const float*)d_in[2];
  const float* dtb  = (const float*)d_in[3];
  const float* Alog = (const float*)d_in[4];
  const float* Dv   = (const float*)d_in[5];
  const float* opw  = (const float*)d_in[6];
  const float* opb  = (const float*)d_in[7];
  float* out = (float*)d_out;

  char* ws = (char*)d_ws;
  float*          xdbc  = (float*)(ws);                         // 5,242,880
  unsigned short* dtmp  = (unsigned short*)(ws + 5242880);      // 2,097,152
  unsigned short* delta = (unsigned short*)(ws + 7340032);      // 33,554,432
  unsigned short* ybf   = (unsigned short*)(ws + 40894464);     // 33,554,432
  unsigned short* w3b   = (unsigned short*)(ws + 74448896);     // 8,388,608
  float*          Hloc  = (float*)(ws + 82837504);              // 16,777,216
  float*          Hinit = (float*)(ws + 99614720);              // 16,777,216
  float*          Ssum  = (float*)(ws + 116391936);             // 1,048,576
  unsigned short* xpwb  = (unsigned short*)(ws + 117440512);    // 655,360
  unsigned short* dtwb  = (unsigned short*)(ws + 118095872);    // 524,288
  // total ws use: 118,620,160 B

  // weight casts -> bf16
  cast_kernel<<<dim3((D_MODEL * D_MODEL) / 2048), 256, 0, stream>>>(opw, w3b);
  cast_kernel<<<dim3((NPROJ * D_MODEL) / 2048), 256, 0, stream>>>(xpw, xpwb);
  cast_kernel<<<dim3((D_MODEL * DT_RANK) / 2048), 256, 0, stream>>>(dtw, dtwb);

  // GEMM1: xdbc[8192,160] = hs @ xpw^T ; dtmp = bf16(xdbc[:, :128]). Single col pass.
  gemm_nt<64, 160, 2, 2, false, true, 0>
      <<<dim3(MROWS / 64, 1), 256, 0, stream>>>(
      hs, nullptr, nullptr, xpwb, D_MODEL, xdbc, dtmp, nullptr);

  // GEMM2: delta = softplus(dtmp @ dtw^T + dtb) (bf16), 256x128 pipelined kernel
  gemm_big<1><<<dim3(512), 512, 0, stream>>>(
      dtmp, dtwb, DT_RANK, nullptr, delta, dtb, nullptr, nullptr);

  // Chunked scan: P1 -> prop -> P2
  scan_chunk<false><<<dim3(D_MODEL / 256, NCHUNK, B_SZ), 256, 0, stream>>>(
      delta, hs, xdbc, Alog, Ssum, Hloc, nullptr, nullptr);
  scan_prop<<<dim3((B_SZ * D_MODEL * D_STATE) / 256), 256, 0, stream>>>(
      Alog, Ssum, Hloc, Hinit);
  scan_chunk<true><<<dim3(D_MODEL / 256, NCHUNK, B_SZ), 256, 0, stream>>>(
      delta, hs, xdbc, Alog, nullptr, nullptr, Hinit, ybf);

  // GEMM3: out = relu(ybf @ w3b^T + opb) + D*hs, 256x128 pipelined kernel
  gemm_big<2><<<dim3(512), 512, 0, stream>>>(
      ybf, w3b, D_MODEL, out, nullptr, opb, Dv, hs);

  (void)in_sizes; (void)n_in; (void)out_size; (void)ws_size;
}

// Round 5
// 440.384 us; speedup vs baseline: 3.1331x; 1.0769x over previous
//
#include <hip/hip_runtime.h>
#include <hip/hip_bf16.h>
#include <stdint.h>

// ---------------- problem constants ----------------
#define D_MODEL 2048
#define D_STATE 16
#define DT_RANK 128
#define B_SZ 4
#define SEQLEN 2048
#define MROWS (B_SZ * SEQLEN)          // 8192
#define NPROJ (DT_RANK + 2 * D_STATE)  // 160
#define NCHUNK 32
#define CHUNK (SEQLEN / NCHUNK)        // 64

typedef short bf16x8 __attribute__((ext_vector_type(8)));
typedef unsigned short ushort8 __attribute__((ext_vector_type(8)));
typedef float f32x4 __attribute__((ext_vector_type(4)));

__device__ __forceinline__ unsigned short f2bf(float f) {
  union { float f; uint32_t u; } a; a.f = f;
  uint32_t u = a.u;
  u += 0x7fffu + ((u >> 16) & 1u);
  return (unsigned short)(u >> 16);
}
__device__ __forceinline__ float bf2f(unsigned short h) {
  union { uint32_t u; float f; } a; a.u = ((uint32_t)h) << 16;
  return a.f;
}

__device__ __forceinline__ void async16(const void* g, void* l) {
  __builtin_amdgcn_global_load_lds((const __attribute__((address_space(1))) void*)g,
                                   (__attribute__((address_space(3))) void*)(uintptr_t)l,
                                   16, 0, 0);
}

// fast softplus: ~10 VALU ops, rel err ~1e-6 (<< bf16 rounding)
__device__ __forceinline__ float softplus_fast(float s) {
  float e = __expf(-fabsf(s));
  return fmaxf(s, 0.f) + __logf(1.f + e);
}

// ---------------------------------------------------------------------------
// gemm_k128 (GEMM2): delta[8192,2048] = softplus(dtmp[8192,128] @ dtw[2048,128]^T
//                    + bias), bf16 out. K=128 -> ONE LDS staging, no K loop.
// 128x128 tile, 256 thr = 4 waves (2x2, wave tile 64x64), 64KB LDS -> 2 blk/CU.
// XOR swizzle byte^=(row&7)<<4 (256B rows): stage source chunk gc=c^((c>>4)&7),
// linear LDS dest, swizzled ds_read (same involution; R4-verified, 0 conflicts).
// ---------------------------------------------------------------------------
__global__ __launch_bounds__(256)
void gemm_k128(const unsigned short* __restrict__ A, const unsigned short* __restrict__ B,
               unsigned short* __restrict__ outb, const float* __restrict__ bias)
{
  __shared__ char smA[128 * 256];   // [128][128] bf16, 256B rows
  __shared__ char smB[128 * 256];

  const int tid  = threadIdx.x;
  const int lane = tid & 63;
  const int wid  = tid >> 6;
  const int wrow = (wid >> 1) * 64;
  const int wcol = (wid & 1) * 64;
  const int row0 = blockIdx.x * 128;
  const int col0 = blockIdx.y * 128;

  #pragma unroll
  for (int it = 0; it < 8; ++it) {
    int c = it * 256 + tid;
    int gc = c ^ ((c >> 4) & 7);
    async16((const char*)(A + (size_t)(row0 + (gc >> 4)) * DT_RANK) + (gc & 15) * 16,
            smA + (c & ~63) * 16);
  }
  #pragma unroll
  for (int it = 0; it < 8; ++it) {
    int c = it * 256 + tid;
    int gc = c ^ ((c >> 4) & 7);
    async16((const char*)(B + (size_t)(col0 + (gc >> 4)) * DT_RANK) + (gc & 15) * 16,
            smB + (c & ~63) * 16);
  }
  __syncthreads();   // drains vmcnt (global_load_lds)

  f32x4 acc[4][4] = {};
  #pragma unroll
  for (int kk = 0; kk < 4; ++kk) {
    bf16x8 a[4], b[4];
    #pragma unroll
    for (int i = 0; i < 4; ++i) {
      int r = wrow + i * 16 + (lane & 15);
      int byt = r * 256 + kk * 64 + ((lane >> 4) * 16);
      a[i] = *reinterpret_cast<const bf16x8*>(smA + (byt ^ ((r & 7) << 4)));
    }
    #pragma unroll
    for (int j = 0; j < 4; ++j) {
      int r = wcol + j * 16 + (lane & 15);
      int byt = r * 256 + kk * 64 + ((lane >> 4) * 16);
      b[j] = *reinterpret_cast<const bf16x8*>(smB + (byt ^ ((r & 7) << 4)));
    }
    #pragma unroll
    for (int i = 0; i < 4; ++i)
      #pragma unroll
      for (int j = 0; j < 4; ++j)
        acc[i][j] = __builtin_amdgcn_mfma_f32_16x16x32_bf16(a[i], b[j], acc[i][j], 0, 0, 0);
  }

  // epilogue: hoist per-lane bias (4 cols/thread), fast softplus, bf16 store
  float sbias[4];
  #pragma unroll
  for (int j = 0; j < 4; ++j) sbias[j] = bias[col0 + wcol + j * 16 + (lane & 15)];
  #pragma unroll
  for (int i = 0; i < 4; ++i) {
    #pragma unroll
    for (int j = 0; j < 4; ++j) {
      #pragma unroll
      for (int r = 0; r < 4; ++r) {
        int grow = row0 + wrow + i * 16 + ((lane >> 4) * 4) + r;
        int gcol = col0 + wcol + j * 16 + (lane & 15);
        outb[(size_t)grow * D_MODEL + gcol] = f2bf(softplus_fast(acc[i][j][r] + sbias[j]));
      }
    }
  }
}

// ---------------------------------------------------------------------------
// Generic NT GEMM (R2-proven): C[M,N] = A[M,K] * B[N,K]^T. BK=32, 256 thr,
// 4 waves WMv x WNv. EPI: 0 = x-proj (f32 [*,160] + bf16 dtmp col<128),
// 2 = relu(acc+bias)+D*hs -> f32.
// ---------------------------------------------------------------------------
template<int BM, int BN, int WMv, int WNv, bool A_BF, bool B_BF, int EPI>
__global__ __launch_bounds__(256)
void gemm_nt(const float* __restrict__ Af, const unsigned short* __restrict__ Ab,
             const float* __restrict__ Bf, const unsigned short* __restrict__ Bb,
             int K,
             float* __restrict__ outf, unsigned short* __restrict__ outb,
             const float* __restrict__ bias, const float* __restrict__ Dvec,
             const float* __restrict__ hsres)
{
  constexpr int TM = BM / WMv, TN = BN / WNv;
  constexpr int FM = TM / 16, FN = TN / 16;
  __shared__ char smem[(BM + BN) * 64];
  char* smA = smem;
  char* smB = smem + BM * 64;

  const int tid  = threadIdx.x;
  const int lane = tid & 63;
  const int wid  = tid >> 6;
  const int wm   = wid / WNv, wn = wid % WNv;
  const int wrow = wm * TM,  wcol = wn * TN;
  const int row0 = blockIdx.x * BM;
  const int col0 = blockIdx.y * BN;

  f32x4 acc[FM][FN] = {};

  for (int k0 = 0; k0 < K; k0 += 32) {
    { // A tile [BM][32]
      constexpr int CH = BM * 4;
      #pragma unroll
      for (int it = 0; it < (CH + 255) / 256; ++it) {
        int c = it * 256 + tid;
        if ((CH % 256 == 0) || (c < CH)) {
          if constexpr (A_BF) {
            const char* g = (const char*)(Ab + (size_t)(row0 + (c >> 2)) * K + k0) + (c & 3) * 16;
            async16(g, smA + (c & ~63) * 16);
          } else {
            const float* g = Af + (size_t)(row0 + (c >> 2)) * K + k0 + (c & 3) * 8;
            float4 u = *reinterpret_cast<const float4*>(g);
            float4 v = *reinterpret_cast<const float4*>(g + 4);
            ushort8 p;
            p[0] = f2bf(u.x); p[1] = f2bf(u.y); p[2] = f2bf(u.z); p[3] = f2bf(u.w);
            p[4] = f2bf(v.x); p[5] = f2bf(v.y); p[6] = f2bf(v.z); p[7] = f2bf(v.w);
            *reinterpret_cast<ushort8*>(smA + c * 16) = p;
          }
        }
      }
    }
    { // B tile [BN][32]
      constexpr int CH = BN * 4;
      #pragma unroll
      for (int it = 0; it < (CH + 255) / 256; ++it) {
        int c = it * 256 + tid;
        if ((CH % 256 == 0) || (c < CH)) {
          if constexpr (B_BF) {
            const char* g = (const char*)(Bb + (size_t)(col0 + (c >> 2)) * K + k0) + (c & 3) * 16;
            async16(g, smB + (c & ~63) * 16);
          } else {
            const float* g = Bf + (size_t)(col0 + (c >> 2)) * K + k0 + (c & 3) * 8;
            float4 u = *reinterpret_cast<const float4*>(g);
            float4 v = *reinterpret_cast<const float4*>(g + 4);
            ushort8 p;
            p[0] = f2bf(u.x); p[1] = f2bf(u.y); p[2] = f2bf(u.z); p[3] = f2bf(u.w);
            p[4] = f2bf(v.x); p[5] = f2bf(v.y); p[6] = f2bf(v.z); p[7] = f2bf(v.w);
            *reinterpret_cast<ushort8*>(smB + c * 16) = p;
          }
        }
      }
    }
    __syncthreads();

    bf16x8 a[FM], b[FN];
    const int kb = (lane >> 4) * 16;
    #pragma unroll
    for (int i = 0; i < FM; ++i)
      a[i] = *reinterpret_cast<const bf16x8*>(smA + (wrow + i * 16 + (lane & 15)) * 64 + kb);
    #pragma unroll
    for (int j = 0; j < FN; ++j)
      b[j] = *reinterpret_cast<const bf16x8*>(smB + (wcol + j * 16 + (lane & 15)) * 64 + kb);
    #pragma unroll
    for (int i = 0; i < FM; ++i)
      #pragma unroll
      for (int j = 0; j < FN; ++j)
        acc[i][j] = __builtin_amdgcn_mfma_f32_16x16x32_bf16(a[i], b[j], acc[i][j], 0, 0, 0);
    __syncthreads();
  }

  #pragma unroll
  for (int i = 0; i < FM; ++i) {
    #pragma unroll
    for (int j = 0; j < FN; ++j) {
      #pragma unroll
      for (int r = 0; r < 4; ++r) {
        int grow = row0 + wrow + i * 16 + ((lane >> 4) * 4) + r;
        int gcol = col0 + wcol + j * 16 + (lane & 15);
        float v = acc[i][j][r];
        if constexpr (EPI == 0) {
          outf[(size_t)grow * NPROJ + gcol] = v;
          if (gcol < DT_RANK) outb[(size_t)grow * DT_RANK + gcol] = f2bf(v);
        } else {
          float s = fmaxf(v + bias[gcol], 0.f)
                    + Dvec[gcol] * hsres[(size_t)grow * D_MODEL + gcol];
          outf[(size_t)grow * D_MODEL + gcol] = s;
        }
      }
    }
  }
}

// ---------------------------------------------------------------------------
// Chunked selective scan (R1-proven, unchanged).
// ---------------------------------------------------------------------------
template<bool P2>
__global__ __launch_bounds__(256)
void scan_chunk(const unsigned short* __restrict__ delta,
                const float* __restrict__ hs,
                const float* __restrict__ xdbc,
                const float* __restrict__ A_log,
                float* __restrict__ Ssum, float* __restrict__ Hloc,
                const float* __restrict__ Hinit,
                unsigned short* __restrict__ y)
{
  const int b  = blockIdx.z;
  const int c  = blockIdx.y;
  const int d  = blockIdx.x * 256 + threadIdx.x;
  const int t0 = c * CHUNK;
  __shared__ float Bs[CHUNK][16];
  __shared__ float Cs[P2 ? CHUNK : 1][16];

  {
    int tt = threadIdx.x >> 2, nn = (threadIdx.x & 3) * 4;
    const float* src = xdbc + (size_t)(b * SEQLEN + t0 + tt) * NPROJ + DT_RANK;
    *reinterpret_cast<float4*>(&Bs[tt][nn]) = *reinterpret_cast<const float4*>(src + nn);
    if constexpr (P2)
      *reinterpret_cast<float4*>(&Cs[tt][nn]) = *reinterpret_cast<const float4*>(src + D_STATE + nn);
  }

  float A[16], h[16];
  #pragma unroll
  for (int n = 0; n < 16; ++n) A[n] = -__expf(A_log[d * 16 + n]);
  const size_t hoff = ((size_t)((b * NCHUNK + c) * D_MODEL) + d) * 16;
  if constexpr (P2) {
    #pragma unroll
    for (int n = 0; n < 16; ++n) h[n] = Hinit[hoff + n];
  } else {
    #pragma unroll
    for (int n = 0; n < 16; ++n) h[n] = 0.f;
  }
  __syncthreads();

  float S = 0.f;
  const size_t rbase = (size_t)(b * SEQLEN + t0) * D_MODEL + d;
  #pragma unroll 2
  for (int t = 0; t < CHUNK; ++t) {
    float dlt = bf2f(delta[rbase + (size_t)t * D_MODEL]);
    float x   = hs[rbase + (size_t)t * D_MODEL];
    float dx  = dlt * x;
    S += dlt;
    float yv = 0.f;
    #pragma unroll
    for (int n = 0; n < 16; ++n) {
      float dA = __expf(dlt * A[n]);
      h[n] = fmaf(h[n], dA, dx * Bs[t][n]);
      if constexpr (P2) yv = fmaf(h[n], Cs[t][n], yv);
    }
    if constexpr (P2) y[rbase + (size_t)t * D_MODEL] = f2bf(yv);
  }

  if constexpr (!P2) {
    Ssum[(size_t)((b * NCHUNK + c) * D_MODEL) + d] = S;
    #pragma unroll
    for (int n = 0; n < 16; ++n) Hloc[hoff + n] = h[n];
  }
}

__global__ __launch_bounds__(256)
void scan_prop(const float* __restrict__ A_log, const float* __restrict__ Ssum,
               const float* __restrict__ Hloc, float* __restrict__ Hinit)
{
  int idx = blockIdx.x * 256 + threadIdx.x;
  int n = idx & 15, d = (idx >> 4) & (D_MODEL - 1), b = idx >> 15;
  float A = -__expf(A_log[d * D_STATE + n]);
  float H = 0.f;
  for (int c = 0; c < NCHUNK; ++c) {
    size_t off = ((size_t)((b * NCHUNK + c) * D_MODEL) + d) * 16 + n;
    Hinit[off] = H;
    float P = __expf(A * Ssum[(size_t)((b * NCHUNK + c) * D_MODEL) + d]);
    H = fmaf(H, P, Hloc[off]);
  }
}

__global__ __launch_bounds__(256)
void cast_kernel(const float* __restrict__ in, unsigned short* __restrict__ out)
{
  int i = (blockIdx.x * 256 + threadIdx.x) * 8;
  float4 u = *reinterpret_cast<const float4*>(in + i);
  float4 v = *reinterpret_cast<const float4*>(in + i + 4);
  ushort8 p;
  p[0] = f2bf(u.x); p[1] = f2bf(u.y); p[2] = f2bf(u.z); p[3] = f2bf(u.w);
  p[4] = f2bf(v.x); p[5] = f2bf(v.y); p[6] = f2bf(v.z); p[7] = f2bf(v.w);
  *reinterpret_cast<ushort8*>(out + i) = p;
}

// ---------------------------------------------------------------------------
extern "C" void kernel_launch(void* const* d_in, const int* in_sizes, int n_in,
                              void* d_out, int out_size, void* d_ws, size_t ws_size,
                              hipStream_t stream)
{
  const float* hs   = (const float*)d_in[0];
  const float* xpw  = (const float*)d_in[1];
  const float* dtw  = (const float*)d_in[2];
  const float* dtb  = (const float*)d_in[3];
  const float* Alog = (const float*)d_in[4];
  const float* Dv   = (const float*)d_in[5];
  const float* opw  = (const float*)d_in[6];
  const float* opb  = (const float*)d_in[7];
  float* out = (float*)d_out;

  char* ws = (char*)d_ws;
  float*          xdbc  = (float*)(ws);                         // 5,242,880
  unsigned short* dtmp  = (unsigned short*)(ws + 5242880);      // 2,097,152
  unsigned short* delta = (unsigned short*)(ws + 7340032);      // 33,554,432
  unsigned short* ybf   = (unsigned short*)(ws + 40894464);     // 33,554,432
  unsigned short* w3b   = (unsigned short*)(ws + 74448896);     // 8,388,608
  float*          Hloc  = (float*)(ws + 82837504);              // 16,777,216
  float*          Hinit = (float*)(ws + 99614720);              // 16,777,216
  float*          Ssum  = (float*)(ws + 116391936);             // 1,048,576
  unsigned short* xpwb  = (unsigned short*)(ws + 117440512);    // 655,360
  unsigned short* dtwb  = (unsigned short*)(ws + 118095872);    // 524,288
  // total ws use: 118,620,160 B

  // weight casts -> bf16
  cast_kernel<<<dim3((D_MODEL * D_MODEL) / 2048), 256, 0, stream>>>(opw, w3b);
  cast_kernel<<<dim3((NPROJ * D_MODEL) / 2048), 256, 0, stream>>>(xpw, xpwb);
  cast_kernel<<<dim3((D_MODEL * DT_RANK) / 2048), 256, 0, stream>>>(dtw, dtwb);

  // GEMM1: xdbc[8192,160] = hs @ xpw^T ; dtmp = bf16(xdbc[:, :128]).
  // BM=32 -> 256 blocks (full GPU), single column pass.
  gemm_nt<32, 160, 2, 2, false, true, 0>
      <<<dim3(MROWS / 32, 1), 256, 0, stream>>>(
      hs, nullptr, nullptr, xpwb, D_MODEL, xdbc, dtmp, nullptr, nullptr, nullptr);

  // GEMM2: delta = softplus(dtmp @ dtw^T + dtb), single-staging K=128 kernel
  gemm_k128<<<dim3(MROWS / 128, D_MODEL / 128), 256, 0, stream>>>(
      dtmp, dtwb, delta, dtb);

  // Chunked scan: P1 -> prop -> P2
  scan_chunk<false><<<dim3(D_MODEL / 256, NCHUNK, B_SZ), 256, 0, stream>>>(
      delta, hs, xdbc, Alog, Ssum, Hloc, nullptr, nullptr);
  scan_prop<<<dim3((B_SZ * D_MODEL * D_STATE) / 256), 256, 0, stream>>>(
      Alog, Ssum, Hloc, Hinit);
  scan_chunk<true><<<dim3(D_MODEL / 256, NCHUNK, B_SZ), 256, 0, stream>>>(
      delta, hs, xdbc, Alog, nullptr, nullptr, Hinit, ybf);

  // GEMM3: out = relu(ybf @ w3b^T + opb) + D*hs  (R2-proven structure, 125 us)
  gemm_nt<128, 128, 2, 2, true, true, 2>
      <<<dim3(MROWS / 128, D_MODEL / 128), 256, 0, stream>>>(
      nullptr, ybf, nullptr, w3b, D_MODEL, out, nullptr, opb, Dv, hs);

  (void)in_sizes; (void)n_in; (void)out_size; (void)ws_size;
}